// Round 1
// baseline (312.476 us; speedup 1.0000x reference)
//
#include <hip/hip_runtime.h>

// ============================================================================
// FilteredTensorProduct: out[n,c] = sum_{a,b} x1[n,a] x2[n,b] ww3j[a,b,c]
//   ww3j = sum_p weights[p] * W3J[p]   (23 SO(3) CG paths, lmax=3, dims 16)
//
// Strategy:
//  - constexpr entry table of all structurally-nonzero (a,b,c) triples
//    (359 entries) derived from real-spherical-harmonic product selection
//    rules (cos/sin angular-momentum addition). Pattern is compile time;
//    VALUES are runtime (depend on weights).
//  - cg_setup_kernel (23 blocks): computes real-basis CG values in fp64 on
//    device (exact transcription of the reference math) and writes the
//    compacted coefficient array (359 floats) to d_ws.
//  - tp_kernel: thread-per-row, fully unrolled sparse contraction. Coefs are
//    wave-uniform: striped into 6 VGPRs/lane, broadcast via v_readlane with
//    compile-time lane index -> SGPR operand of v_fma. x1/x2/acc all in
//    registers with compile-time indices. Memory-bound by design.
// ============================================================================

// ---------------- compile-time sparsity pattern ----------------
struct Tables {
  int npaths;
  int pl1[32], pl2[32], plo[32];
  int nent;
  int pstart[33];
  unsigned char ea[512], eb[512], ec[512];
};

constexpr Tables build_tables() {
  Tables t{};
  for (int lo = 0; lo <= 3; ++lo)
    for (int l1 = 0; l1 <= 3; ++l1)
      for (int l2 = 0; l2 <= 3; ++l2) {
        if (((l1 + l2 + lo) & 1) != 0) continue;           // parity rule
        int lmin = l1 > l2 ? l1 - l2 : l2 - l1;
        if (lo > l1 + l2 || lo < lmin) continue;           // triangle rule
        int p = t.npaths;
        t.pl1[p] = l1; t.pl2[p] = l2; t.plo[p] = lo;
        t.pstart[p] = t.nent;
        int o1 = l1 * l1, o2 = l2 * l2, oo = lo * lo;
        for (int m1 = -l1; m1 <= l1; ++m1)
          for (int m2 = -l2; m2 <= l2; ++m2) {
            int cand[2]; int nc = 0;
            if (m1 == 0) cand[nc++] = m2;                  // Y_{l,0} has no phi dep
            else if (m2 == 0) cand[nc++] = m1;
            else {
              int u = m1 < 0 ? -m1 : m1, v = m2 < 0 ? -m2 : m2;
              int d = u > v ? u - v : v - u;
              if ((m1 > 0) == (m2 > 0)) {                  // cos*cos or sin*sin -> cos
                cand[nc++] = u + v; cand[nc++] = d;
              } else {                                     // sin*cos -> sin
                cand[nc++] = -(u + v);
                if (d) cand[nc++] = -d;                    // sin(0) == 0
              }
            }
            for (int q = 0; q < nc; ++q) {
              int m3 = cand[q];
              int am3 = m3 < 0 ? -m3 : m3;
              if (am3 <= lo) {
                t.ea[t.nent] = (unsigned char)(o1 + l1 + m1);
                t.eb[t.nent] = (unsigned char)(o2 + l2 + m2);
                t.ec[t.nent] = (unsigned char)(oo + lo + m3);
                ++t.nent;
              }
            }
          }
        ++t.npaths;
        t.pstart[t.npaths] = t.nent;
      }
  return t;
}

constexpr Tables TBL = build_tables();
constexpr int NENT = TBL.nent;                 // expected 359
constexpr int NCREG = (NENT + 63) / 64;        // coef VGPRs per lane

// ---------------- device CG math (fp64, transcribes reference) -------------
__device__ __constant__ double FACT[11] = {
    1., 1., 2., 6., 24., 120., 720., 5040., 40320., 362880., 3628800.};

struct cplx { double re, im; };

__device__ inline double su2_cg(int j1, int m1, int j2, int m2, int j3, int m3) {
  if (m3 != m1 + m2) return 0.0;
  int vmin = -j1 + j2 + m3;
  if (-j1 + m1 > vmin) vmin = -j1 + m1;
  if (0 > vmin) vmin = 0;
  int vmax = j2 + j3 + m1;
  if (j3 - j1 + j2 < vmax) vmax = j3 - j1 + j2;
  if (j3 + m3 < vmax) vmax = j3 + m3;
  double C = (2.0 * j3 + 1.0) *
             (FACT[j3 + j1 - j2] * FACT[j3 - j1 + j2] * FACT[j1 + j2 - j3] *
              FACT[j3 + m3] * FACT[j3 - m3]) /
             (FACT[j1 + j2 + j3 + 1] * FACT[j1 - m1] * FACT[j1 + m1] *
              FACT[j2 - m2] * FACT[j2 + m2]);
  double S = 0.0;
  for (int v = vmin; v <= vmax; ++v) {
    double t = (FACT[j2 + j3 + m1 - v] * FACT[j1 - m1 + v]) /
               (FACT[v] * FACT[j3 - j1 + j2 - v] * FACT[j3 + m3 - v] *
                FACT[v + j1 - j2 - m3]);
    S += (((v + j2 + m2) & 1) ? -1.0 : 1.0) * t;
  }
  return sqrt(C) * S;
}

// q[l+m, l+-|m|] of _change_basis_real_to_complex, incl. global (-i)^l phase.
// r = first index (complex m), c = second index.
__device__ inline cplx Qmat(int l, int r, int c) {
  int m = r - l, mc = c - l;
  const double is2 = 0.70710678118654752440;
  double re = 0.0, im = 0.0;
  if (m < 0) {
    if (mc == -m) re = is2;          // q[l+m, l+|m|] = 1/sqrt2
    else if (mc == m) im = -is2;     // q[l+m, l-|m|] = -i/sqrt2
  } else if (m == 0) {
    if (mc == 0) re = 1.0;
  } else {
    double s = (m & 1) ? -is2 : is2; // (-1)^m / sqrt2
    if (mc == m) re = s;
    else if (mc == -m) im = s;
  }
  cplx out;
  switch (l & 3) {                   // multiply by (-i)^l
    case 0: out.re = re;  out.im = im;  break;
    case 1: out.re = im;  out.im = -re; break;
    case 2: out.re = -re; out.im = -im; break;
    default: out.re = -im; out.im = re; break;
  }
  return out;
}

// One block per path. Computes Creal[j,l,m] = Re(Q1^T ... einsum) staged
// through LDS, then writes weights[p]*sqrt(2lo+1)*Creal into the compact
// coefficient slots of this path.
__global__ void cg_setup_kernel(const float* __restrict__ weights,
                                float* __restrict__ wwc) {
  const int p = blockIdx.x;
  const int l1 = TBL.pl1[p], l2 = TBL.pl2[p], lo = TBL.plo[p];
  const int n1 = 2 * l1 + 1, n2 = 2 * l2 + 1, n3 = 2 * lo + 1;
  const int tot = n1 * n2 * n3;
  const int tid = (int)threadIdx.x;
  const int bd = (int)blockDim.x;

  __shared__ double Cs[343];
  __shared__ double Vr[343], Vi[343];
  __shared__ double Ur[343], Ui[343];
  __shared__ double Rr[343];

  // stage 0: SU(2) CG tensor Cs[i,k,n]
  for (int idx = tid; idx < tot; idx += bd) {
    int i = idx / (n2 * n3), r = idx % (n2 * n3);
    int k = r / n3, nn = r % n3;
    Cs[idx] = su2_cg(l1, i - l1, l2, k - l2, lo, nn - lo);
  }
  __syncthreads();

  // stage A: V[i,k,m] = sum_n Cs[i,k,n] * conj(Q3[n,m])
  for (int idx = tid; idx < tot; idx += bd) {
    int i = idx / (n2 * n3), r = idx % (n2 * n3);
    int k = r / n3, m = r % n3;
    double vr = 0.0, vi = 0.0;
    for (int nn = 0; nn < n3; ++nn) {
      double c = Cs[(i * n2 + k) * n3 + nn];
      cplx q = Qmat(lo, nn, m);
      vr += c * q.re;
      vi -= c * q.im;
    }
    Vr[idx] = vr; Vi[idx] = vi;
  }
  __syncthreads();

  // stage B: U[i,l,m] = sum_k Q2[k,l] * V[i,k,m]
  for (int idx = tid; idx < tot; idx += bd) {
    int i = idx / (n2 * n3), r = idx % (n2 * n3);
    int l = r / n3, m = r % n3;
    double ur = 0.0, ui = 0.0;
    for (int k = 0; k < n2; ++k) {
      cplx q = Qmat(l2, k, l);
      double vr = Vr[(i * n2 + k) * n3 + m];
      double vi = Vi[(i * n2 + k) * n3 + m];
      ur += q.re * vr - q.im * vi;
      ui += q.re * vi + q.im * vr;
    }
    Ur[idx] = ur; Ui[idx] = ui;
  }
  __syncthreads();

  // stage C: R[j,l,m] = Re( sum_i Q1[i,j] * U[i,l,m] )
  for (int idx = tid; idx < tot; idx += bd) {
    int j = idx / (n2 * n3), r = idx % (n2 * n3);
    int l = r / n3, m = r % n3;
    double rr = 0.0;
    for (int i = 0; i < n1; ++i) {
      cplx q = Qmat(l1, i, j);
      rr += q.re * Ur[(i * n2 + l) * n3 + m] - q.im * Ui[(i * n2 + l) * n3 + m];
    }
    Rr[idx] = rr;
  }
  __syncthreads();

  // write compacted coefficients for this path
  const double ws = (double)weights[p] * sqrt(2.0 * lo + 1.0);
  const int o1 = l1 * l1, o2 = l2 * l2, oo = lo * lo;
  for (int e = TBL.pstart[p] + tid; e < TBL.pstart[p + 1]; e += bd) {
    int i = (int)TBL.ea[e] - o1;
    int j = (int)TBL.eb[e] - o2;
    int k = (int)TBL.ec[e] - oo;
    wwc[e] = (float)(ws * Rr[(i * n2 + j) * n3 + k]);
  }
}

// ---------------- main contraction kernel ----------------
__global__ __launch_bounds__(256) void tp_kernel(const float* __restrict__ x1,
                                                 const float* __restrict__ x2,
                                                 const float* __restrict__ wwc,
                                                 float* __restrict__ out,
                                                 int n) {
  const int lane = (int)threadIdx.x & 63;

  // Preload coefficients striped across lanes: lane L holds wwc[L + 64k].
  // Done before any divergence so every lane's VGPRs are valid for readlane.
  float creg[NCREG];
#pragma unroll
  for (int k = 0; k < NCREG; ++k) creg[k] = wwc[k * 64 + lane];

  const int row = (int)blockIdx.x * 256 + (int)threadIdx.x;
  if (row >= n) return;

  const float4* X1 = reinterpret_cast<const float4*>(x1) + (size_t)row * 4;
  const float4* X2 = reinterpret_cast<const float4*>(x2) + (size_t)row * 4;

  float a[16], b[16];
#pragma unroll
  for (int q = 0; q < 4; ++q) {
    float4 t = X1[q];
    a[4 * q + 0] = t.x; a[4 * q + 1] = t.y; a[4 * q + 2] = t.z; a[4 * q + 3] = t.w;
    float4 u = X2[q];
    b[4 * q + 0] = u.x; b[4 * q + 1] = u.y; b[4 * q + 2] = u.z; b[4 * q + 3] = u.w;
  }

  float acc[16];
#pragma unroll
  for (int c = 0; c < 16; ++c) acc[c] = 0.0f;

#pragma unroll
  for (int e = 0; e < NENT; ++e) {
    // wave-uniform coefficient -> SGPR via readlane (compile-time lane idx)
    int wbits = __builtin_amdgcn_readlane(__float_as_int(creg[e >> 6]), e & 63);
    float w = __int_as_float(wbits);
    acc[TBL.ec[e]] = fmaf(w, a[TBL.ea[e]] * b[TBL.eb[e]], acc[TBL.ec[e]]);
  }

  float4* O = reinterpret_cast<float4*>(out) + (size_t)row * 4;
#pragma unroll
  for (int q = 0; q < 4; ++q) {
    O[q] = make_float4(acc[4 * q + 0], acc[4 * q + 1], acc[4 * q + 2],
                       acc[4 * q + 3]);
  }
}

// ---------------- launch ----------------
extern "C" void kernel_launch(void* const* d_in, const int* in_sizes, int n_in,
                              void* d_out, int out_size, void* d_ws,
                              size_t ws_size, hipStream_t stream) {
  const float* x1 = (const float*)d_in[0];
  const float* x2 = (const float*)d_in[1];
  const float* w  = (const float*)d_in[2];
  float* out = (float*)d_out;
  float* wwc = (float*)d_ws;   // NENT (+pad) compacted coefficients

  const int n = in_sizes[0] / 16;

  // 1) compute compacted ww3j coefficients (23 tiny blocks)
  cg_setup_kernel<<<dim3(TBL.npaths), dim3(256), 0, stream>>>(w, wwc);

  // 2) sparse per-row contraction
  const int grid = (n + 255) / 256;
  tp_kernel<<<dim3(grid), dim3(256), 0, stream>>>(x1, x2, wwc, out, n);
}